// Round 7
// baseline (443.566 us; speedup 1.0000x reference)
//
#include <hip/hip_runtime.h>
#include <hip/hip_bf16.h>
#include <stdint.h>

typedef __attribute__((ext_vector_type(8))) short short8;
typedef __attribute__((ext_vector_type(4))) short short4v;
typedef __attribute__((ext_vector_type(4))) float floatx4;
typedef __hip_bfloat16 bf16;

__device__ __forceinline__ float b2f(bf16 v) { return __bfloat162float(v); }
__device__ __forceinline__ bf16 f2b(float v) { return __float2bfloat16(v); }
__device__ __forceinline__ float gelu_f(float v) {
    return 0.5f * v * (1.0f + erff(v * 0.70710678118654752f));
}

#define GLD_LDS16(gptr, lptr) \
  __builtin_amdgcn_global_load_lds((const __attribute__((address_space(1))) void*)(gptr), \
                                   (__attribute__((address_space(3))) void*)(lptr), 16, 0, 0)

// ---------------- CSR build (group edges by dst) ----------------
__global__ void k_count(const int* __restrict__ dst, int* __restrict__ cnt, int E) {
    int e = blockIdx.x * blockDim.x + threadIdx.x;
    if (e < E) atomicAdd(&cnt[dst[e]], 1);
}

// n must be 32768: 1024 threads x 32 elements each
__global__ __launch_bounds__(1024) void k_scan(const int* __restrict__ cnt,
                                               int* __restrict__ row_ptr,
                                               int* __restrict__ fill, int n) {
    __shared__ int sdata[1024];
    int t = threadIdx.x;
    int base = t * 32;
    int local[32];
    int sum = 0;
    #pragma unroll
    for (int k = 0; k < 32; k++) { local[k] = sum; sum += cnt[base + k]; }
    sdata[t] = sum;
    __syncthreads();
    for (int off = 1; off < 1024; off <<= 1) {
        int v = (t >= off) ? sdata[t - off] : 0;
        __syncthreads();
        sdata[t] += v;
        __syncthreads();
    }
    int excl = sdata[t] - sum;
    #pragma unroll
    for (int k = 0; k < 32; k++) {
        int v = excl + local[k];
        row_ptr[base + k] = v;
        fill[base + k] = v;
    }
    if (t == 1023) row_ptr[n] = excl + sum;
}

__global__ void k_scatter(const int* __restrict__ src, const int* __restrict__ dst,
                          int* __restrict__ fill, int* __restrict__ col, int E) {
    int e = blockIdx.x * blockDim.x + threadIdx.x;
    if (e < E) {
        int p = atomicAdd(&fill[dst[e]], 1);
        col[p] = src[e];
    }
}

// ---------------- all four weight transposes (both layers) in one launch ----------------
// Wt[layer][512][256] bf16: rows 0..255 = W_l columns, 256..511 = W_r columns
__global__ void k_transpose4(const float* __restrict__ Wl1, const float* __restrict__ Wr1,
                             const float* __restrict__ Wl2, const float* __restrict__ Wr2,
                             bf16* __restrict__ Wt) {
    int r = blockIdx.x & 255, half = (blockIdx.x >> 8) & 1, layer = blockIdx.x >> 9;
    int c = threadIdx.x;
    const float* W = layer ? (half ? Wr2 : Wl2) : (half ? Wr1 : Wl1);
    Wt[(size_t)(layer * 512 + half * 256 + c) * 256 + r] = f2b(W[r * 256 + c]);
}

// ---------------- fused MFMA GEMM: C[M,512] = A[M,K] @ Bt[512,K]^T + bias ----------------
// 128x128 tile per 256-thread block, BK=64. B via global_load_lds (m97).
// A: fp32 (layer 1, reg-staged + converted) or bf16 (layer 2, global_load_lds).
template <bool AF32>
__global__ __launch_bounds__(256) void k_gemm(const void* __restrict__ Av,
                                              const bf16* __restrict__ Bt,
                                              const float* __restrict__ biasL,
                                              const float* __restrict__ biasR,
                                              bf16* __restrict__ C,
                                              int M, int K) {
    __shared__ bf16 As[128 * 64];   // [m][k]
    __shared__ bf16 Bs[128 * 64];   // [n][k]
    const int tid  = threadIdx.x;
    const int wave = tid >> 6;
    const int lane = tid & 63;
    const int quad = lane >> 4;
    const int l16  = lane & 15;
    const int m0 = blockIdx.x * 128;
    const int n0 = blockIdx.y * 128;
    const int wm = (wave & 1) * 64;
    const int wn = (wave >> 1) * 64;

    floatx4 acc[4][4] = {};

    for (int k0 = 0; k0 < K; k0 += 64) {
        #pragma unroll
        for (int i = 0; i < 4; i++) {
            if (AF32) {
                const float* A = (const float*)Av;
                int flat = (i * 256 + tid) * 8;
                int row  = flat >> 6;
                int colk = flat & 63;
                const float* ap = A + (size_t)(m0 + row) * K + k0 + colk;
                bf16 tmp[8];
                #pragma unroll
                for (int q = 0; q < 8; q++) tmp[q] = f2b(ap[q]);
                *(short8*)&As[row * 64 + colk] = *(const short8*)tmp;
            } else {
                const bf16* A = (const bf16*)Av;
                int chunk = i * 4 + wave;
                int foff  = (chunk * 64 + lane) * 16;
                int row   = foff >> 7;
                int cole  = (foff & 127) >> 1;
                GLD_LDS16(A + (size_t)(m0 + row) * K + k0 + cole,
                          (char*)As + chunk * 1024 + lane * 16);
            }
            {
                int chunk = i * 4 + wave;
                int foff  = (chunk * 64 + lane) * 16;
                int row   = foff >> 7;
                int cole  = (foff & 127) >> 1;
                GLD_LDS16(Bt + (size_t)(n0 + row) * K + k0 + cole,
                          (char*)Bs + chunk * 1024 + lane * 16);
            }
        }
        __syncthreads();   // drains vmcnt+lgkmcnt before s_barrier
        #pragma unroll
        for (int ks = 0; ks < 2; ks++) {
            short8 af[4], bfr[4];
            #pragma unroll
            for (int i = 0; i < 4; i++) {
                af[i]  = *(const short8*)&As[(wm + i * 16 + l16) * 64 + ks * 32 + quad * 8];
                bfr[i] = *(const short8*)&Bs[(wn + i * 16 + l16) * 64 + ks * 32 + quad * 8];
            }
            #pragma unroll
            for (int i = 0; i < 4; i++)
                #pragma unroll
                for (int j = 0; j < 4; j++)
                    acc[i][j] = __builtin_amdgcn_mfma_f32_16x16x32_bf16(af[i], bfr[j], acc[i][j], 0, 0, 0);
        }
        __syncthreads();
    }

    // C/D layout: col = lane&15, row = quad*4 + reg  [verified m89/m91]
    #pragma unroll
    for (int j = 0; j < 4; j++) {
        int gcol = n0 + wn + j * 16 + l16;
        float bv = (gcol < 256) ? biasL[gcol] : biasR[gcol - 256];
        #pragma unroll
        for (int i = 0; i < 4; i++) {
            #pragma unroll
            for (int r = 0; r < 4; r++) {
                int grow = m0 + wm + i * 16 + quad * 4 + r;
                C[(size_t)grow * 512 + gcol] = f2b(acc[i][j][r] + bv);
            }
        }
    }
}

// ---------------- GATv2 aggregation: one wave per dst node, max-free softmax ----------------
// leaky(u) = 0.6u + 0.4|u| folded into att: logit = sum(att6*u) + sum(att4*|u|).
// Logits bounded (max over E ~7.5) -> exp safe in fp32, no running max.
// lane: head = l>>4, channels (l&15)*4..+3; 4-step shfl reduce within 16 lanes.
__global__ __launch_bounds__(256) void k_agg(const bf16* __restrict__ xlr,
                                             const float* __restrict__ att,
                                             const int* __restrict__ row_ptr,
                                             const int* __restrict__ col,
                                             const float* __restrict__ bias,
                                             bf16* __restrict__ out, int do_gelu) {
    int wave = threadIdx.x >> 6, lane = threadIdx.x & 63;
    int i = blockIdx.x * 4 + wave;
    int f = (lane >> 4) * 64 + (lane & 15) * 4;

    floatx4 attv = *(const floatx4*)(att + f);
    float att6[4], att4[4];
    #pragma unroll
    for (int j = 0; j < 4; j++) { att6[j] = 0.6f * attv[j]; att4[j] = 0.4f * attv[j]; }

    float xr_v[4], xs[4];
    {
        bf16 t[4];
        *(short4v*)t = *(const short4v*)(xlr + (size_t)i * 512 + 256 + f);
        #pragma unroll
        for (int j = 0; j < 4; j++) xr_v[j] = b2f(t[j]);
        *(short4v*)t = *(const short4v*)(xlr + (size_t)i * 512 + f);
        #pragma unroll
        for (int j = 0; j < 4; j++) xs[j] = b2f(t[j]);
    }

    // self-loop
    float lg = 0.f;
    #pragma unroll
    for (int j = 0; j < 4; j++) {
        float u = xs[j] + xr_v[j];
        lg = fmaf(u, att6[j], lg);
        lg = fmaf(fabsf(u), att4[j], lg);
    }
    #pragma unroll
    for (int o = 1; o < 16; o <<= 1) lg += __shfl_xor(lg, o, 16);
    float p0 = __expf(lg);
    float s = p0;
    float acc[4];
    #pragma unroll
    for (int j = 0; j < 4; j++) acc[j] = p0 * xs[j];

    int e0 = row_ptr[i], e1 = row_ptr[i + 1];
    int e = e0;
    for (; e + 2 <= e1; e += 2) {
        int ca = col[e], cb = col[e + 1];
        bf16 ta[4], tb[4];
        *(short4v*)ta = *(const short4v*)(xlr + (size_t)ca * 512 + f);
        *(short4v*)tb = *(const short4v*)(xlr + (size_t)cb * 512 + f);
        float xa[4], xb[4];
        #pragma unroll
        for (int j = 0; j < 4; j++) { xa[j] = b2f(ta[j]); xb[j] = b2f(tb[j]); }
        float la = 0.f, lb = 0.f;
        #pragma unroll
        for (int j = 0; j < 4; j++) {
            float ua = xa[j] + xr_v[j];
            la = fmaf(ua, att6[j], la);
            la = fmaf(fabsf(ua), att4[j], la);
            float ub = xb[j] + xr_v[j];
            lb = fmaf(ub, att6[j], lb);
            lb = fmaf(fabsf(ub), att4[j], lb);
        }
        #pragma unroll
        for (int o = 1; o < 16; o <<= 1) {
            la += __shfl_xor(la, o, 16);
            lb += __shfl_xor(lb, o, 16);
        }
        float pa = __expf(la), pb = __expf(lb);
        s += pa + pb;
        #pragma unroll
        for (int j = 0; j < 4; j++) acc[j] = fmaf(pa, xa[j], fmaf(pb, xb[j], acc[j]));
    }
    if (e < e1) {
        int ca = col[e];
        bf16 ta[4];
        *(short4v*)ta = *(const short4v*)(xlr + (size_t)ca * 512 + f);
        float xa[4];
        #pragma unroll
        for (int j = 0; j < 4; j++) xa[j] = b2f(ta[j]);
        float la = 0.f;
        #pragma unroll
        for (int j = 0; j < 4; j++) {
            float ua = xa[j] + xr_v[j];
            la = fmaf(ua, att6[j], la);
            la = fmaf(fabsf(ua), att4[j], la);
        }
        #pragma unroll
        for (int o = 1; o < 16; o <<= 1) la += __shfl_xor(la, o, 16);
        float pa = __expf(la);
        s += pa;
        #pragma unroll
        for (int j = 0; j < 4; j++) acc[j] = fmaf(pa, xa[j], acc[j]);
    }

    float inv = 1.0f / (s + 1e-16f);
    bf16 ov[4];
    #pragma unroll
    for (int j = 0; j < 4; j++) {
        float v = acc[j] * inv + bias[f + j];
        if (do_gelu) v = gelu_f(v);
        ov[j] = f2b(v);
    }
    *(short4v*)(out + (size_t)i * 256 + f) = *(const short4v*)ov;
}

// ---------------- global mean pool, two-stage ----------------
__global__ __launch_bounds__(256) void k_pool1(const bf16* __restrict__ h,
                                               float* __restrict__ part,
                                               int per_graph, int rows_per) {
    int g = blockIdx.x, p = blockIdx.y, c = threadIdx.x;
    const bf16* base = h + ((size_t)g * per_graph + (size_t)p * rows_per) * 256;
    float acc = 0.f;
    for (int r = 0; r < rows_per; r++) acc += b2f(base[(size_t)r * 256 + c]);
    part[((size_t)g * gridDim.y + p) * 256 + c] = acc;
}
__global__ __launch_bounds__(256) void k_pool2(const float* __restrict__ part,
                                               float* __restrict__ out,
                                               int nparts, int per_graph) {
    int g = blockIdx.x, c = threadIdx.x;
    float acc = 0.f;
    for (int p = 0; p < nparts; p++) acc += part[((size_t)g * nparts + p) * 256 + c];
    out[g * 256 + c] = acc / (float)per_graph;
}

// ---------------- entire MLP head in one kernel: block per graph ----------------
// Weights read in natural [K][N] layout (coalesced across threads) -> no transposes.
__global__ __launch_bounds__(256) void k_headfused(const bf16* __restrict__ hb,
                                                   const float* __restrict__ lin1w,
                                                   const float* __restrict__ lin1b,
                                                   const float* __restrict__ lin2w,
                                                   const float* __restrict__ lin2b,
                                                   const float* __restrict__ finw,
                                                   const float* __restrict__ finb,
                                                   float* __restrict__ out, int PG) {
    __shared__ float zin[256];
    __shared__ float zh[1024];
    __shared__ float z2[256];
    int g = blockIdx.x, t = threadIdx.x;
    zin[t] = b2f(hb[((size_t)g * PG) * 256 + t]);
    __syncthreads();
    // lin1 (256 -> 1024) + GELU
    {
        float a0 = 0.f, a1 = 0.f, a2 = 0.f, a3 = 0.f;
        #pragma unroll 4
        for (int k = 0; k < 256; k++) {
            float v = zin[k];
            const float* wr = lin1w + (size_t)k * 1024 + t;
            a0 = fmaf(v, wr[0],   a0);
            a1 = fmaf(v, wr[256], a1);
            a2 = fmaf(v, wr[512], a2);
            a3 = fmaf(v, wr[768], a3);
        }
        zh[t]       = gelu_f(a0 + lin1b[t]);
        zh[t + 256] = gelu_f(a1 + lin1b[t + 256]);
        zh[t + 512] = gelu_f(a2 + lin1b[t + 512]);
        zh[t + 768] = gelu_f(a3 + lin1b[t + 768]);
    }
    __syncthreads();
    // lin2 (1024 -> 256)
    {
        float a = 0.f;
        #pragma unroll 8
        for (int k = 0; k < 1024; k++)
            a = fmaf(zh[k], lin2w[(size_t)k * 256 + t], a);
        z2[t] = a + lin2b[t];
    }
    __syncthreads();
    // fin (256 -> 512)
    {
        float c0 = 0.f, c1 = 0.f;
        #pragma unroll 4
        for (int k = 0; k < 256; k++) {
            float v = z2[k];
            c0 = fmaf(v, finw[(size_t)k * 512 + t],       c0);
            c1 = fmaf(v, finw[(size_t)k * 512 + t + 256], c1);
        }
        out[(size_t)g * 512 + t]       = c0 + finb[t];
        out[(size_t)g * 512 + t + 256] = c1 + finb[t + 256];
    }
}

extern "C" void kernel_launch(void* const* d_in, const int* in_sizes, int n_in,
                              void* d_out, int out_size, void* d_ws, size_t ws_size,
                              hipStream_t stream) {
    const float* x     = (const float*)d_in[0];
    const int*   ei    = (const int*)d_in[1];
    const float* w1_l  = (const float*)d_in[4];
    const float* b1_l  = (const float*)d_in[5];
    const float* w1_r  = (const float*)d_in[6];
    const float* b1_r  = (const float*)d_in[7];
    const float* att1  = (const float*)d_in[8];
    const float* bias1 = (const float*)d_in[9];
    const float* w2_l  = (const float*)d_in[10];
    const float* b2_l  = (const float*)d_in[11];
    const float* w2_r  = (const float*)d_in[12];
    const float* b2_r  = (const float*)d_in[13];
    const float* att2  = (const float*)d_in[14];
    const float* bias2 = (const float*)d_in[15];
    const float* lin1w = (const float*)d_in[16];
    const float* lin1b = (const float*)d_in[17];
    const float* lin2w = (const float*)d_in[18];
    const float* lin2b = (const float*)d_in[19];
    const float* finw  = (const float*)d_in[20];
    const float* finb  = (const float*)d_in[21];

    const int N  = in_sizes[0] / 256;   // 32768
    const int E  = in_sizes[1] / 2;     // 524288
    const int NG = 64;
    const int PG = N / NG;              // 512

    // workspace layout (~52 MiB)
    char* ws = (char*)d_ws;
    size_t off = 0;
    bf16* xlr = (bf16*)(ws + off); off += (size_t)N * 512 * 2;    // 32 MiB [xl|xr]
    bf16* hb  = (bf16*)(ws + off); off += (size_t)N * 256 * 2;    // 16 MiB (h1 then h2)
    bf16* wt  = (bf16*)(ws + off); off += 2 * 512 * 256 * 2;      // 512 KiB both layers' Wt
    int* row_ptr = (int*)(ws + off); off += (size_t)(N + 2) * 4;
    int* cnt     = (int*)(ws + off); off += (size_t)N * 4;
    int* fill    = (int*)(ws + off); off += (size_t)N * 4;
    int* col     = (int*)(ws + off); off += (size_t)E * 4;
    float* pws   = (float*)(ws + off); off += (size_t)NG * 8 * 256 * 4;  // pool partials

    const int* srcv = ei;
    const int* dstv = ei + E;

    // --- CSR build ---
    hipMemsetAsync(cnt, 0, (size_t)N * 4, stream);
    k_count  <<<E / 256, 256, 0, stream>>>(dstv, cnt, E);
    k_scan   <<<1, 1024, 0, stream>>>(cnt, row_ptr, fill, N);
    k_scatter<<<E / 256, 256, 0, stream>>>(srcv, dstv, fill, col, E);

    // --- both layers' weight transposes, one launch ---
    k_transpose4<<<1024, 256, 0, stream>>>(w1_l, w1_r, w2_l, w2_r, wt);

    dim3 gg(N / 128, 4);   // fused L/R: N-dim 512
    // --- layer 1 (A = x fp32) ---
    k_gemm<true><<<gg, 256, 0, stream>>>(x, wt, b1_l, b1_r, xlr, N, 256);
    k_agg<<<N / 4, 256, 0, stream>>>(xlr, att1, row_ptr, col, bias1, hb, 1);  // + GELU

    // --- layer 2 (A = h1 bf16) ---
    k_gemm<false><<<gg, 256, 0, stream>>>(hb, wt + 512 * 256, b2_l, b2_r, xlr, N, 256);
    k_agg<<<N / 4, 256, 0, stream>>>(xlr, att2, row_ptr, col, bias2, hb, 0);  // h2

    float* outp = (float*)d_out;
    // --- graph mean pool -> d_out[64*512 ..] (output 1) ---
    {
        dim3 gp(NG, 8);
        k_pool1<<<gp, 256, 0, stream>>>(hb, pws, PG, PG / 8);
        k_pool2<<<NG, 256, 0, stream>>>(pws, outp + 64 * 512, 8, PG);
    }
    // --- fused MLP head on node 0 of each graph -> d_out[0 .. 64*512) (output 0) ---
    k_headfused<<<NG, 256, 0, stream>>>(hb, lin1w, lin1b, lin2w, lin2b,
                                        finw, finb, outp, PG);
}

// Round 8
// 396.059 us; speedup vs baseline: 1.1200x; 1.1200x over previous
//
#include <hip/hip_runtime.h>
#include <hip/hip_bf16.h>
#include <stdint.h>

typedef __attribute__((ext_vector_type(8))) short short8;
typedef __attribute__((ext_vector_type(4))) short short4v;
typedef __attribute__((ext_vector_type(4))) float floatx4;
typedef __hip_bfloat16 bf16;

__device__ __forceinline__ float b2f(bf16 v) { return __bfloat162float(v); }
__device__ __forceinline__ bf16 f2b(float v) { return __float2bfloat16(v); }
__device__ __forceinline__ float gelu_f(float v) {
    return 0.5f * v * (1.0f + erff(v * 0.70710678118654752f));
}

#define GLD_LDS16(gptr, lptr) \
  __builtin_amdgcn_global_load_lds((const __attribute__((address_space(1))) void*)(gptr), \
                                   (__attribute__((address_space(3))) void*)(lptr), 16, 0, 0)

// ---------------- CSR build (group edges by dst) ----------------
__global__ void k_count(const int* __restrict__ dst, int* __restrict__ cnt, int E) {
    int e = blockIdx.x * blockDim.x + threadIdx.x;
    if (e < E) atomicAdd(&cnt[dst[e]], 1);
}

// n must be 32768: 1024 threads x 32 elements each
__global__ __launch_bounds__(1024) void k_scan(const int* __restrict__ cnt,
                                               int* __restrict__ row_ptr,
                                               int* __restrict__ fill, int n) {
    __shared__ int sdata[1024];
    int t = threadIdx.x;
    int base = t * 32;
    int local[32];
    int sum = 0;
    #pragma unroll
    for (int k = 0; k < 32; k++) { local[k] = sum; sum += cnt[base + k]; }
    sdata[t] = sum;
    __syncthreads();
    for (int off = 1; off < 1024; off <<= 1) {
        int v = (t >= off) ? sdata[t - off] : 0;
        __syncthreads();
        sdata[t] += v;
        __syncthreads();
    }
    int excl = sdata[t] - sum;
    #pragma unroll
    for (int k = 0; k < 32; k++) {
        int v = excl + local[k];
        row_ptr[base + k] = v;
        fill[base + k] = v;
    }
    if (t == 1023) row_ptr[n] = excl + sum;
}

__global__ void k_scatter(const int* __restrict__ src, const int* __restrict__ dst,
                          int* __restrict__ fill, int* __restrict__ col, int E) {
    int e = blockIdx.x * blockDim.x + threadIdx.x;
    if (e < E) {
        int p = atomicAdd(&fill[dst[e]], 1);
        col[p] = src[e];
    }
}

// ---------------- all four weight transposes (both layers) in one launch ----------------
// Wt[layer][512][256] bf16: rows 0..255 = W_l columns, 256..511 = W_r columns
__global__ void k_transpose4(const float* __restrict__ Wl1, const float* __restrict__ Wr1,
                             const float* __restrict__ Wl2, const float* __restrict__ Wr2,
                             bf16* __restrict__ Wt) {
    int r = blockIdx.x & 255, half = (blockIdx.x >> 8) & 1, layer = blockIdx.x >> 9;
    int c = threadIdx.x;
    const float* W = layer ? (half ? Wr2 : Wl2) : (half ? Wr1 : Wl1);
    Wt[(size_t)(layer * 512 + half * 256 + c) * 256 + r] = f2b(W[r * 256 + c]);
}

// ---------------- fused MFMA GEMM: C[M,512] = A[M,K] @ Bt[512,K]^T + bias ----------------
// 128x128 tile per 256-thread block, BK=64. B via global_load_lds (m97).
// A: fp32 (layer 1, reg-staged + converted) or bf16 (layer 2, global_load_lds).
template <bool AF32>
__global__ __launch_bounds__(256) void k_gemm(const void* __restrict__ Av,
                                              const bf16* __restrict__ Bt,
                                              const float* __restrict__ biasL,
                                              const float* __restrict__ biasR,
                                              bf16* __restrict__ C,
                                              int M, int K) {
    __shared__ bf16 As[128 * 64];   // [m][k]
    __shared__ bf16 Bs[128 * 64];   // [n][k]
    const int tid  = threadIdx.x;
    const int wave = tid >> 6;
    const int lane = tid & 63;
    const int quad = lane >> 4;
    const int l16  = lane & 15;
    const int m0 = blockIdx.x * 128;
    const int n0 = blockIdx.y * 128;
    const int wm = (wave & 1) * 64;
    const int wn = (wave >> 1) * 64;

    floatx4 acc[4][4] = {};

    for (int k0 = 0; k0 < K; k0 += 64) {
        #pragma unroll
        for (int i = 0; i < 4; i++) {
            if (AF32) {
                const float* A = (const float*)Av;
                int flat = (i * 256 + tid) * 8;
                int row  = flat >> 6;
                int colk = flat & 63;
                const float* ap = A + (size_t)(m0 + row) * K + k0 + colk;
                bf16 tmp[8];
                #pragma unroll
                for (int q = 0; q < 8; q++) tmp[q] = f2b(ap[q]);
                *(short8*)&As[row * 64 + colk] = *(const short8*)tmp;
            } else {
                const bf16* A = (const bf16*)Av;
                int chunk = i * 4 + wave;
                int foff  = (chunk * 64 + lane) * 16;
                int row   = foff >> 7;
                int cole  = (foff & 127) >> 1;
                GLD_LDS16(A + (size_t)(m0 + row) * K + k0 + cole,
                          (char*)As + chunk * 1024 + lane * 16);
            }
            {
                int chunk = i * 4 + wave;
                int foff  = (chunk * 64 + lane) * 16;
                int row   = foff >> 7;
                int cole  = (foff & 127) >> 1;
                GLD_LDS16(Bt + (size_t)(n0 + row) * K + k0 + cole,
                          (char*)Bs + chunk * 1024 + lane * 16);
            }
        }
        __syncthreads();   // drains vmcnt+lgkmcnt before s_barrier
        #pragma unroll
        for (int ks = 0; ks < 2; ks++) {
            short8 af[4], bfr[4];
            #pragma unroll
            for (int i = 0; i < 4; i++) {
                af[i]  = *(const short8*)&As[(wm + i * 16 + l16) * 64 + ks * 32 + quad * 8];
                bfr[i] = *(const short8*)&Bs[(wn + i * 16 + l16) * 64 + ks * 32 + quad * 8];
            }
            #pragma unroll
            for (int i = 0; i < 4; i++)
                #pragma unroll
                for (int j = 0; j < 4; j++)
                    acc[i][j] = __builtin_amdgcn_mfma_f32_16x16x32_bf16(af[i], bfr[j], acc[i][j], 0, 0, 0);
        }
        __syncthreads();
    }

    // C/D layout: col = lane&15, row = quad*4 + reg  [verified m89/m91]
    #pragma unroll
    for (int j = 0; j < 4; j++) {
        int gcol = n0 + wn + j * 16 + l16;
        float bv = (gcol < 256) ? biasL[gcol] : biasR[gcol - 256];
        #pragma unroll
        for (int i = 0; i < 4; i++) {
            #pragma unroll
            for (int r = 0; r < 4; r++) {
                int grow = m0 + wm + i * 16 + quad * 4 + r;
                C[(size_t)grow * 512 + gcol] = f2b(acc[i][j][r] + bv);
            }
        }
    }
}

// ---------------- GATv2 aggregation: one wave per dst node, max-free softmax ----------------
// leaky(u) = 0.6u + 0.4|u| folded into att: logit = sum(att6*u) + sum(att4*|u|).
// Logits bounded (max over E ~7.5) -> exp safe in fp32, no running max.
// lane: head = l>>4, channels (l&15)*4..+3; 4-step shfl reduce within 16 lanes.
__global__ __launch_bounds__(256) void k_agg(const bf16* __restrict__ xlr,
                                             const float* __restrict__ att,
                                             const int* __restrict__ row_ptr,
                                             const int* __restrict__ col,
                                             const float* __restrict__ bias,
                                             bf16* __restrict__ out, int do_gelu) {
    int wave = threadIdx.x >> 6, lane = threadIdx.x & 63;
    int i = blockIdx.x * 4 + wave;
    int f = (lane >> 4) * 64 + (lane & 15) * 4;

    floatx4 attv = *(const floatx4*)(att + f);
    float att6[4], att4[4];
    #pragma unroll
    for (int j = 0; j < 4; j++) { att6[j] = 0.6f * attv[j]; att4[j] = 0.4f * attv[j]; }

    float xr_v[4], xs[4];
    {
        bf16 t[4];
        *(short4v*)t = *(const short4v*)(xlr + (size_t)i * 512 + 256 + f);
        #pragma unroll
        for (int j = 0; j < 4; j++) xr_v[j] = b2f(t[j]);
        *(short4v*)t = *(const short4v*)(xlr + (size_t)i * 512 + f);
        #pragma unroll
        for (int j = 0; j < 4; j++) xs[j] = b2f(t[j]);
    }

    // self-loop
    float lg = 0.f;
    #pragma unroll
    for (int j = 0; j < 4; j++) {
        float u = xs[j] + xr_v[j];
        lg = fmaf(u, att6[j], lg);
        lg = fmaf(fabsf(u), att4[j], lg);
    }
    #pragma unroll
    for (int o = 1; o < 16; o <<= 1) lg += __shfl_xor(lg, o, 16);
    float p0 = __expf(lg);
    float s = p0;
    float acc[4];
    #pragma unroll
    for (int j = 0; j < 4; j++) acc[j] = p0 * xs[j];

    int e0 = row_ptr[i], e1 = row_ptr[i + 1];
    int e = e0;
    for (; e + 2 <= e1; e += 2) {
        int ca = col[e], cb = col[e + 1];
        bf16 ta[4], tb[4];
        *(short4v*)ta = *(const short4v*)(xlr + (size_t)ca * 512 + f);
        *(short4v*)tb = *(const short4v*)(xlr + (size_t)cb * 512 + f);
        float xa[4], xb[4];
        #pragma unroll
        for (int j = 0; j < 4; j++) { xa[j] = b2f(ta[j]); xb[j] = b2f(tb[j]); }
        float la = 0.f, lb = 0.f;
        #pragma unroll
        for (int j = 0; j < 4; j++) {
            float ua = xa[j] + xr_v[j];
            la = fmaf(ua, att6[j], la);
            la = fmaf(fabsf(ua), att4[j], la);
            float ub = xb[j] + xr_v[j];
            lb = fmaf(ub, att6[j], lb);
            lb = fmaf(fabsf(ub), att4[j], lb);
        }
        #pragma unroll
        for (int o = 1; o < 16; o <<= 1) {
            la += __shfl_xor(la, o, 16);
            lb += __shfl_xor(lb, o, 16);
        }
        float pa = __expf(la), pb = __expf(lb);
        s += pa + pb;
        #pragma unroll
        for (int j = 0; j < 4; j++) acc[j] = fmaf(pa, xa[j], fmaf(pb, xb[j], acc[j]));
    }
    if (e < e1) {
        int ca = col[e];
        bf16 ta[4];
        *(short4v*)ta = *(const short4v*)(xlr + (size_t)ca * 512 + f);
        float xa[4];
        #pragma unroll
        for (int j = 0; j < 4; j++) xa[j] = b2f(ta[j]);
        float la = 0.f;
        #pragma unroll
        for (int j = 0; j < 4; j++) {
            float ua = xa[j] + xr_v[j];
            la = fmaf(ua, att6[j], la);
            la = fmaf(fabsf(ua), att4[j], la);
        }
        #pragma unroll
        for (int o = 1; o < 16; o <<= 1) la += __shfl_xor(la, o, 16);
        float pa = __expf(la);
        s += pa;
        #pragma unroll
        for (int j = 0; j < 4; j++) acc[j] = fmaf(pa, xa[j], acc[j]);
    }

    float inv = 1.0f / (s + 1e-16f);
    bf16 ov[4];
    #pragma unroll
    for (int j = 0; j < 4; j++) {
        float v = acc[j] * inv + bias[f + j];
        if (do_gelu) v = gelu_f(v);
        ov[j] = f2b(v);
    }
    *(short4v*)(out + (size_t)i * 256 + f) = *(const short4v*)ov;
}

// ---------------- global mean pool, two-stage ----------------
__global__ __launch_bounds__(256) void k_pool1(const bf16* __restrict__ h,
                                               float* __restrict__ part,
                                               int per_graph, int rows_per) {
    int g = blockIdx.x, p = blockIdx.y, c = threadIdx.x;
    const bf16* base = h + ((size_t)g * per_graph + (size_t)p * rows_per) * 256;
    float acc = 0.f;
    for (int r = 0; r < rows_per; r++) acc += b2f(base[(size_t)r * 256 + c]);
    part[((size_t)g * gridDim.y + p) * 256 + c] = acc;
}
__global__ __launch_bounds__(256) void k_pool2(const float* __restrict__ part,
                                               float* __restrict__ out,
                                               int nparts, int per_graph) {
    int g = blockIdx.x, c = threadIdx.x;
    float acc = 0.f;
    for (int p = 0; p < nparts; p++) acc += part[((size_t)g * nparts + p) * 256 + c];
    out[g * 256 + c] = acc / (float)per_graph;
}

// ---------------- head layer: block per (graph, 64-col chunk), split-K ----------------
// Natural [K][N] weight layout (no transpose). Input row staged in LDS (broadcast).
// 256 threads = 64 columns x 4 K-quarters; LDS combine of the 4 partials.
__global__ __launch_bounds__(256) void k_head2(const bf16* __restrict__ inB,
                                               const float* __restrict__ inF,
                                               const float* __restrict__ W,
                                               const float* __restrict__ bias,
                                               float* __restrict__ out,
                                               int K, int N, long long row_stride, int act) {
    __shared__ float zin[1024];
    __shared__ float red[256];
    int g = blockIdx.x;
    int t = threadIdx.x;
    int nc = t & 63;               // column within this block's 64-chunk
    int kq = t >> 6;               // K-quarter 0..3
    int n = blockIdx.y * 64 + nc;
    for (int k = t; k < K; k += 256)
        zin[k] = inB ? b2f(inB[(size_t)g * row_stride + k])
                     : inF[(size_t)g * row_stride + k];
    __syncthreads();
    const int klen = K >> 2;
    const int kb = kq * klen;
    float acc = 0.f;
    #pragma unroll 8
    for (int k = 0; k < klen; k++)
        acc = fmaf(zin[kb + k], W[(size_t)(kb + k) * N + n], acc);
    red[t] = acc;
    __syncthreads();
    if (kq == 0) {
        float v = red[nc] + red[nc + 64] + red[nc + 128] + red[nc + 192] + bias[n];
        if (act) v = gelu_f(v);
        out[(size_t)g * N + n] = v;
    }
}

extern "C" void kernel_launch(void* const* d_in, const int* in_sizes, int n_in,
                              void* d_out, int out_size, void* d_ws, size_t ws_size,
                              hipStream_t stream) {
    const float* x     = (const float*)d_in[0];
    const int*   ei    = (const int*)d_in[1];
    const float* w1_l  = (const float*)d_in[4];
    const float* b1_l  = (const float*)d_in[5];
    const float* w1_r  = (const float*)d_in[6];
    const float* b1_r  = (const float*)d_in[7];
    const float* att1  = (const float*)d_in[8];
    const float* bias1 = (const float*)d_in[9];
    const float* w2_l  = (const float*)d_in[10];
    const float* b2_l  = (const float*)d_in[11];
    const float* w2_r  = (const float*)d_in[12];
    const float* b2_r  = (const float*)d_in[13];
    const float* att2  = (const float*)d_in[14];
    const float* bias2 = (const float*)d_in[15];
    const float* lin1w = (const float*)d_in[16];
    const float* lin1b = (const float*)d_in[17];
    const float* lin2w = (const float*)d_in[18];
    const float* lin2b = (const float*)d_in[19];
    const float* finw  = (const float*)d_in[20];
    const float* finb  = (const float*)d_in[21];

    const int N  = in_sizes[0] / 256;   // 32768
    const int E  = in_sizes[1] / 2;     // 524288
    const int NG = 64;
    const int PG = N / NG;              // 512

    // workspace layout (~52.5 MiB)
    char* ws = (char*)d_ws;
    size_t off = 0;
    bf16* xlr = (bf16*)(ws + off); off += (size_t)N * 512 * 2;    // 32 MiB [xl|xr]
    bf16* hb  = (bf16*)(ws + off); off += (size_t)N * 256 * 2;    // 16 MiB (h1 then h2)
    bf16* wt  = (bf16*)(ws + off); off += 2 * 512 * 256 * 2;      // 512 KiB both layers' Wt
    int* row_ptr = (int*)(ws + off); off += (size_t)(N + 2) * 4;
    int* cnt     = (int*)(ws + off); off += (size_t)N * 4;
    int* fill    = (int*)(ws + off); off += (size_t)N * 4;
    int* col     = (int*)(ws + off); off += (size_t)E * 4;
    float* pws   = (float*)(ws + off); off += (size_t)NG * 8 * 256 * 4;  // pool partials
    float* t1    = (float*)(ws + off); off += (size_t)NG * 1024 * 4;
    float* t2    = (float*)(ws + off); off += (size_t)NG * 256 * 4;

    const int* srcv = ei;
    const int* dstv = ei + E;

    // --- CSR build ---
    hipMemsetAsync(cnt, 0, (size_t)N * 4, stream);
    k_count  <<<E / 256, 256, 0, stream>>>(dstv, cnt, E);
    k_scan   <<<1, 1024, 0, stream>>>(cnt, row_ptr, fill, N);
    k_scatter<<<E / 256, 256, 0, stream>>>(srcv, dstv, fill, col, E);

    // --- both layers' weight transposes, one launch ---
    k_transpose4<<<1024, 256, 0, stream>>>(w1_l, w1_r, w2_l, w2_r, wt);

    dim3 gg(N / 128, 4);   // fused L/R: N-dim 512
    // --- layer 1 (A = x fp32) ---
    k_gemm<true><<<gg, 256, 0, stream>>>(x, wt, b1_l, b1_r, xlr, N, 256);
    k_agg<<<N / 4, 256, 0, stream>>>(xlr, att1, row_ptr, col, bias1, hb, 1);  // + GELU

    // --- layer 2 (A = h1 bf16) ---
    k_gemm<false><<<gg, 256, 0, stream>>>(hb, wt + 512 * 256, b2_l, b2_r, xlr, N, 256);
    k_agg<<<N / 4, 256, 0, stream>>>(xlr, att2, row_ptr, col, bias2, hb, 0);  // h2

    float* outp = (float*)d_out;
    // --- graph mean pool -> d_out[64*512 ..] (output 1) ---
    {
        dim3 gp(NG, 8);
        k_pool1<<<gp, 256, 0, stream>>>(hb, pws, PG, PG / 8);
        k_pool2<<<NG, 256, 0, stream>>>(pws, outp + 64 * 512, 8, PG);
    }
    // --- MLP head on node 0 of each graph -> d_out[0 .. 64*512) (output 0) ---
    {
        dim3 h1(NG, 1024 / 64);
        k_head2<<<h1, 256, 0, stream>>>(hb, nullptr, lin1w, lin1b, t1,
                                        256, 1024, (long long)PG * 256, 1);
        dim3 h2(NG, 256 / 64);
        k_head2<<<h2, 256, 0, stream>>>(nullptr, t1, lin2w, lin2b, t2,
                                        1024, 256, 1024, 0);
        dim3 h3(NG, 512 / 64);
        k_head2<<<h3, 256, 0, stream>>>(nullptr, t2, finw, finb, outp,
                                        256, 512, 256, 0);
    }
}

// Round 9
// 381.542 us; speedup vs baseline: 1.1626x; 1.0380x over previous
//
#include <hip/hip_runtime.h>
#include <hip/hip_bf16.h>
#include <stdint.h>

typedef __attribute__((ext_vector_type(8))) short short8;
typedef __attribute__((ext_vector_type(4))) short short4v;
typedef __attribute__((ext_vector_type(4))) float floatx4;
typedef __hip_bfloat16 bf16;

__device__ __forceinline__ float b2f(bf16 v) { return __bfloat162float(v); }
__device__ __forceinline__ bf16 f2b(float v) { return __float2bfloat16(v); }
__device__ __forceinline__ float gelu_f(float v) {
    return 0.5f * v * (1.0f + erff(v * 0.70710678118654752f));
}

#define GLD_LDS16(gptr, lptr) \
  __builtin_amdgcn_global_load_lds((const __attribute__((address_space(1))) void*)(gptr), \
                                   (__attribute__((address_space(3))) void*)(lptr), 16, 0, 0)

// ---------------- CSR build (group edges by dst), 4 edges/thread ----------------
__global__ void k_count(const int* __restrict__ dst, int* __restrict__ cnt, int E) {
    int g = blockIdx.x * blockDim.x + threadIdx.x;
    if (g * 4 < E) {
        int4 d = ((const int4*)dst)[g];
        atomicAdd(&cnt[d.x], 1);
        atomicAdd(&cnt[d.y], 1);
        atomicAdd(&cnt[d.z], 1);
        atomicAdd(&cnt[d.w], 1);
    }
}

// n must be 32768: 1024 threads x 32 elements each
__global__ __launch_bounds__(1024) void k_scan(const int* __restrict__ cnt,
                                               int* __restrict__ row_ptr,
                                               int* __restrict__ fill, int n) {
    __shared__ int sdata[1024];
    int t = threadIdx.x;
    int base = t * 32;
    int local[32];
    int sum = 0;
    #pragma unroll
    for (int k = 0; k < 32; k++) { local[k] = sum; sum += cnt[base + k]; }
    sdata[t] = sum;
    __syncthreads();
    for (int off = 1; off < 1024; off <<= 1) {
        int v = (t >= off) ? sdata[t - off] : 0;
        __syncthreads();
        sdata[t] += v;
        __syncthreads();
    }
    int excl = sdata[t] - sum;
    #pragma unroll
    for (int k = 0; k < 32; k++) {
        int v = excl + local[k];
        row_ptr[base + k] = v;
        fill[base + k] = v;
    }
    if (t == 1023) row_ptr[n] = excl + sum;
}

__global__ void k_scatter(const int* __restrict__ src, const int* __restrict__ dst,
                          int* __restrict__ fill, int* __restrict__ col, int E) {
    int g = blockIdx.x * blockDim.x + threadIdx.x;
    if (g * 4 < E) {
        int4 d = ((const int4*)dst)[g];
        int4 sv = ((const int4*)src)[g];
        int p;
        p = atomicAdd(&fill[d.x], 1); col[p] = sv.x;
        p = atomicAdd(&fill[d.y], 1); col[p] = sv.y;
        p = atomicAdd(&fill[d.z], 1); col[p] = sv.z;
        p = atomicAdd(&fill[d.w], 1); col[p] = sv.w;
    }
}

// ---------------- all four weight transposes (both layers) in one launch ----------------
// Wt[layer][512][256] bf16: rows 0..255 = W_l columns, 256..511 = W_r columns
__global__ void k_transpose4(const float* __restrict__ Wl1, const float* __restrict__ Wr1,
                             const float* __restrict__ Wl2, const float* __restrict__ Wr2,
                             bf16* __restrict__ Wt) {
    int r = blockIdx.x & 255, half = (blockIdx.x >> 8) & 1, layer = blockIdx.x >> 9;
    int c = threadIdx.x;
    const float* W = layer ? (half ? Wr2 : Wl2) : (half ? Wr1 : Wl1);
    Wt[(size_t)(layer * 512 + half * 256 + c) * 256 + r] = f2b(W[r * 256 + c]);
}

// ---------------- fused MFMA GEMM: C[M,512] = A[M,K] @ Bt[512,K]^T + bias ----------------
// grid (4, M/128): the 4 N-tile blocks sharing an A-tile are dispatch-adjacent -> L2 A reuse.
// 128x128 tile per 256-thread block, BK=64. B via global_load_lds (m97).
template <bool AF32>
__global__ __launch_bounds__(256) void k_gemm(const void* __restrict__ Av,
                                              const bf16* __restrict__ Bt,
                                              const float* __restrict__ biasL,
                                              const float* __restrict__ biasR,
                                              bf16* __restrict__ C,
                                              int M, int K) {
    __shared__ bf16 As[128 * 64];   // [m][k]
    __shared__ bf16 Bs[128 * 64];   // [n][k]
    const int tid  = threadIdx.x;
    const int wave = tid >> 6;
    const int lane = tid & 63;
    const int quad = lane >> 4;
    const int l16  = lane & 15;
    const int m0 = blockIdx.y * 128;
    const int n0 = blockIdx.x * 128;
    const int wm = (wave & 1) * 64;
    const int wn = (wave >> 1) * 64;

    floatx4 acc[4][4] = {};

    for (int k0 = 0; k0 < K; k0 += 64) {
        #pragma unroll
        for (int i = 0; i < 4; i++) {
            if (AF32) {
                const float* A = (const float*)Av;
                int flat = (i * 256 + tid) * 8;
                int row  = flat >> 6;
                int colk = flat & 63;
                const float* ap = A + (size_t)(m0 + row) * K + k0 + colk;
                bf16 tmp[8];
                #pragma unroll
                for (int q = 0; q < 8; q++) tmp[q] = f2b(ap[q]);
                *(short8*)&As[row * 64 + colk] = *(const short8*)tmp;
            } else {
                const bf16* A = (const bf16*)Av;
                int chunk = i * 4 + wave;
                int foff  = (chunk * 64 + lane) * 16;
                int row   = foff >> 7;
                int cole  = (foff & 127) >> 1;
                GLD_LDS16(A + (size_t)(m0 + row) * K + k0 + cole,
                          (char*)As + chunk * 1024 + lane * 16);
            }
            {
                int chunk = i * 4 + wave;
                int foff  = (chunk * 64 + lane) * 16;
                int row   = foff >> 7;
                int cole  = (foff & 127) >> 1;
                GLD_LDS16(Bt + (size_t)(n0 + row) * K + k0 + cole,
                          (char*)Bs + chunk * 1024 + lane * 16);
            }
        }
        __syncthreads();   // drains vmcnt+lgkmcnt before s_barrier
        #pragma unroll
        for (int ks = 0; ks < 2; ks++) {
            short8 af[4], bfr[4];
            #pragma unroll
            for (int i = 0; i < 4; i++) {
                af[i]  = *(const short8*)&As[(wm + i * 16 + l16) * 64 + ks * 32 + quad * 8];
                bfr[i] = *(const short8*)&Bs[(wn + i * 16 + l16) * 64 + ks * 32 + quad * 8];
            }
            #pragma unroll
            for (int i = 0; i < 4; i++)
                #pragma unroll
                for (int j = 0; j < 4; j++)
                    acc[i][j] = __builtin_amdgcn_mfma_f32_16x16x32_bf16(af[i], bfr[j], acc[i][j], 0, 0, 0);
        }
        __syncthreads();
    }

    // C/D layout: col = lane&15, row = quad*4 + reg  [verified m89/m91]
    #pragma unroll
    for (int j = 0; j < 4; j++) {
        int gcol = n0 + wn + j * 16 + l16;
        float bv = (gcol < 256) ? biasL[gcol] : biasR[gcol - 256];
        #pragma unroll
        for (int i = 0; i < 4; i++) {
            #pragma unroll
            for (int r = 0; r < 4; r++) {
                int grow = m0 + wm + i * 16 + quad * 4 + r;
                C[(size_t)grow * 512 + gcol] = f2b(acc[i][j][r] + bv);
            }
        }
    }
}

// ---------------- GATv2 aggregation: half-wave per edge, 8 ch/lane ----------------
// One wave per dst node. Lanes 0-31 = item a, 32-63 = item b of each pair.
// Within a half: 8 lanes per head (hl>>3), 8 channels per lane ((hl&7)*8).
// Item 0 = self-loop, items 1..deg = CSR edges. Max-free softmax (logits bounded),
// leaky folded into att (0.6u + 0.4|u|). 2-deep pipelined col+gather prefetch.
__global__ __launch_bounds__(256) void k_agg(const bf16* __restrict__ xlr,
                                             const float* __restrict__ att,
                                             const int* __restrict__ row_ptr,
                                             const int* __restrict__ col,
                                             const float* __restrict__ bias,
                                             bf16* __restrict__ out, int do_gelu) {
    int wave = threadIdx.x >> 6, lane = threadIdx.x & 63;
    int i = blockIdx.x * 4 + wave;
    int hl = lane & 31;
    int half = lane >> 5;
    int f = (hl >> 3) * 64 + (hl & 7) * 8;

    float att6[8], att4[8], xr_v[8];
    {
        floatx4 a0 = *(const floatx4*)(att + f);
        floatx4 a1 = *(const floatx4*)(att + f + 4);
        #pragma unroll
        for (int j = 0; j < 4; j++) {
            att6[j]     = 0.6f * a0[j]; att4[j]     = 0.4f * a0[j];
            att6[4 + j] = 0.6f * a1[j]; att4[4 + j] = 0.4f * a1[j];
        }
        bf16 t[8];
        *(short8*)t = *(const short8*)(xlr + (size_t)i * 512 + 256 + f);
        #pragma unroll
        for (int j = 0; j < 8; j++) xr_v[j] = b2f(t[j]);
    }

    int e0 = row_ptr[i], e1 = row_ptr[i + 1];
    int total = 1 + (e1 - e0);   // self + in-edges

    // prologue: resolve + issue gather for pair 0; resolve col for pair 1
    int src_c = i;
    if (half == 1 && total > 1) src_c = col[e0];
    bf16 g_cur[8];
    *(short8*)g_cur = *(const short8*)(xlr + (size_t)src_c * 512 + f);
    int t1 = 2 + half;
    int src_n = (t1 < total) ? col[e0 + t1 - 1] : i;

    float s = 0.f, acc[8] = {};

    for (int base = 0; base < total; base += 2) {
        // issue gather for pair+1 (address resolved last iteration)
        bf16 g_nxt[8];
        *(short8*)g_nxt = *(const short8*)(xlr + (size_t)src_n * 512 + f);
        // resolve col for pair+2
        int t2 = base + 4 + half;
        int src_n2 = (t2 < total) ? col[e0 + t2 - 1] : i;
        // compute current pair
        bool valid = (base + half) < total;
        float xv[8], l = 0.f;
        #pragma unroll
        for (int j = 0; j < 8; j++) {
            xv[j] = b2f(g_cur[j]);
            float u = xv[j] + xr_v[j];
            l = fmaf(u, att6[j], fmaf(fabsf(u), att4[j], l));
        }
        l += __shfl_xor(l, 1, 8);
        l += __shfl_xor(l, 2, 8);
        l += __shfl_xor(l, 4, 8);
        float p = valid ? __expf(l) : 0.f;
        s += p;
        #pragma unroll
        for (int j = 0; j < 8; j++) acc[j] = fmaf(p, xv[j], acc[j]);
        // rotate pipeline
        #pragma unroll
        for (int j = 0; j < 8; j++) g_cur[j] = g_nxt[j];
        src_n = src_n2;
    }

    // combine the two halves
    s += __shfl_xor(s, 32, 64);
    #pragma unroll
    for (int j = 0; j < 8; j++) acc[j] += __shfl_xor(acc[j], 32, 64);

    if (half == 0) {
        float inv = 1.0f / (s + 1e-16f);
        bf16 ov[8];
        #pragma unroll
        for (int j = 0; j < 8; j++) {
            float v = acc[j] * inv + bias[f + j];
            if (do_gelu) v = gelu_f(v);
            ov[j] = f2b(v);
        }
        *(short8*)(out + (size_t)i * 256 + f) = *(const short8*)ov;
    }
}

// ---------------- global mean pool, two-stage ----------------
__global__ __launch_bounds__(256) void k_pool1(const bf16* __restrict__ h,
                                               float* __restrict__ part,
                                               int per_graph, int rows_per) {
    int g = blockIdx.x, p = blockIdx.y, c = threadIdx.x;
    const bf16* base = h + ((size_t)g * per_graph + (size_t)p * rows_per) * 256;
    float acc = 0.f;
    for (int r = 0; r < rows_per; r++) acc += b2f(base[(size_t)r * 256 + c]);
    part[((size_t)g * gridDim.y + p) * 256 + c] = acc;
}
__global__ __launch_bounds__(256) void k_pool2(const float* __restrict__ part,
                                               float* __restrict__ out,
                                               int nparts, int per_graph) {
    int g = blockIdx.x, c = threadIdx.x;
    float acc = 0.f;
    for (int p = 0; p < nparts; p++) acc += part[((size_t)g * nparts + p) * 256 + c];
    out[g * 256 + c] = acc / (float)per_graph;
}

// ---------------- head layer: block per (graph, 64-col chunk), split-K ----------------
__global__ __launch_bounds__(256) void k_head2(const bf16* __restrict__ inB,
                                               const float* __restrict__ inF,
                                               const float* __restrict__ W,
                                               const float* __restrict__ bias,
                                               float* __restrict__ out,
                                               int K, int N, long long row_stride, int act) {
    __shared__ float zin[1024];
    __shared__ float red[256];
    int g = blockIdx.x;
    int t = threadIdx.x;
    int nc = t & 63;
    int kq = t >> 6;
    int n = blockIdx.y * 64 + nc;
    for (int k = t; k < K; k += 256)
        zin[k] = inB ? b2f(inB[(size_t)g * row_stride + k])
                     : inF[(size_t)g * row_stride + k];
    __syncthreads();
    const int klen = K >> 2;
    const int kb = kq * klen;
    float acc = 0.f;
    #pragma unroll 8
    for (int k = 0; k < klen; k++)
        acc = fmaf(zin[kb + k], W[(size_t)(kb + k) * N + n], acc);
    red[t] = acc;
    __syncthreads();
    if (kq == 0) {
        float v = red[nc] + red[nc + 64] + red[nc + 128] + red[nc + 192] + bias[n];
        if (act) v = gelu_f(v);
        out[(size_t)g * N + n] = v;
    }
}

extern "C" void kernel_launch(void* const* d_in, const int* in_sizes, int n_in,
                              void* d_out, int out_size, void* d_ws, size_t ws_size,
                              hipStream_t stream) {
    const float* x     = (const float*)d_in[0];
    const int*   ei    = (const int*)d_in[1];
    const float* w1_l  = (const float*)d_in[4];
    const float* b1_l  = (const float*)d_in[5];
    const float* w1_r  = (const float*)d_in[6];
    const float* b1_r  = (const float*)d_in[7];
    const float* att1  = (const float*)d_in[8];
    const float* bias1 = (const float*)d_in[9];
    const float* w2_l  = (const float*)d_in[10];
    const float* b2_l  = (const float*)d_in[11];
    const float* w2_r  = (const float*)d_in[12];
    const float* b2_r  = (const float*)d_in[13];
    const float* att2  = (const float*)d_in[14];
    const float* bias2 = (const float*)d_in[15];
    const float* lin1w = (const float*)d_in[16];
    const float* lin1b = (const float*)d_in[17];
    const float* lin2w = (const float*)d_in[18];
    const float* lin2b = (const float*)d_in[19];
    const float* finw  = (const float*)d_in[20];
    const float* finb  = (const float*)d_in[21];

    const int N  = in_sizes[0] / 256;   // 32768
    const int E  = in_sizes[1] / 2;     // 524288
    const int NG = 64;
    const int PG = N / NG;              // 512

    // workspace layout (~52.5 MiB)
    char* ws = (char*)d_ws;
    size_t off = 0;
    bf16* xlr = (bf16*)(ws + off); off += (size_t)N * 512 * 2;    // 32 MiB [xl|xr]
    bf16* hb  = (bf16*)(ws + off); off += (size_t)N * 256 * 2;    // 16 MiB (h1 then h2)
    bf16* wt  = (bf16*)(ws + off); off += 2 * 512 * 256 * 2;      // 512 KiB both layers' Wt
    int* row_ptr = (int*)(ws + off); off += (size_t)(N + 2) * 4;
    int* cnt     = (int*)(ws + off); off += (size_t)N * 4;
    int* fill    = (int*)(ws + off); off += (size_t)N * 4;
    int* col     = (int*)(ws + off); off += (size_t)E * 4;
    float* pws   = (float*)(ws + off); off += (size_t)NG * 8 * 256 * 4;  // pool partials
    float* t1    = (float*)(ws + off); off += (size_t)NG * 1024 * 4;
    float* t2    = (float*)(ws + off); off += (size_t)NG * 256 * 4;

    const int* srcv = ei;
    const int* dstv = ei + E;

    // --- CSR build ---
    hipMemsetAsync(cnt, 0, (size_t)N * 4, stream);
    k_count  <<<E / 1024, 256, 0, stream>>>(dstv, cnt, E);
    k_scan   <<<1, 1024, 0, stream>>>(cnt, row_ptr, fill, N);
    k_scatter<<<E / 1024, 256, 0, stream>>>(srcv, dstv, fill, col, E);

    // --- both layers' weight transposes, one launch ---
    k_transpose4<<<1024, 256, 0, stream>>>(w1_l, w1_r, w2_l, w2_r, wt);

    dim3 gg(4, N / 128);   // fused L/R: N-dim 512; A-sharing blocks dispatch-adjacent
    // --- layer 1 (A = x fp32) ---
    k_gemm<true><<<gg, 256, 0, stream>>>(x, wt, b1_l, b1_r, xlr, N, 256);
    k_agg<<<N / 4, 256, 0, stream>>>(xlr, att1, row_ptr, col, bias1, hb, 1);  // + GELU

    // --- layer 2 (A = h1 bf16) ---
    k_gemm<false><<<gg, 256, 0, stream>>>(hb, wt + 512 * 256, b2_l, b2_r, xlr, N, 256);
    k_agg<<<N / 4, 256, 0, stream>>>(xlr, att2, row_ptr, col, bias2, hb, 0);  // h2

    float* outp = (float*)d_out;
    // --- graph mean pool -> d_out[64*512 ..] (output 1) ---
    {
        dim3 gp(NG, 8);
        k_pool1<<<gp, 256, 0, stream>>>(hb, pws, PG, PG / 8);
        k_pool2<<<NG, 256, 0, stream>>>(pws, outp + 64 * 512, 8, PG);
    }
    // --- MLP head on node 0 of each graph -> d_out[0 .. 64*512) (output 0) ---
    {
        dim3 h1(NG, 1024 / 64);
        k_head2<<<h1, 256, 0, stream>>>(hb, nullptr, lin1w, lin1b, t1,
                                        256, 1024, (long long)PG * 256, 1);
        dim3 h2(NG, 256 / 64);
        k_head2<<<h2, 256, 0, stream>>>(nullptr, t1, lin2w, lin2b, t2,
                                        1024, 256, 1024, 0);
        dim3 h3(NG, 512 / 64);
        k_head2<<<h3, 256, 0, stream>>>(nullptr, t2, finw, finb, outp,
                                        256, 512, 256, 0);
    }
}